// Round 5
// baseline (77.971 us; speedup 1.0000x reference)
//
#include <hip/hip_runtime.h>

#define BATCH 1024
#define INSZ 4096
#define SQ 128
#define EM 32
#define NH 8
#define TPB 256

typedef __attribute__((ext_vector_type(8))) __bf16 bf16x8;
typedef __attribute__((ext_vector_type(4))) __bf16 bf16x4;
typedef __attribute__((ext_vector_type(4))) float f32x4;

// One unified 40960-byte LDS region (elem offsets), disjoint lifetimes:
//   [0,5120)      q-stage   [128][LDT=40]   (xn pre-loop; q per head, dies at S2a)
//   [5120,10240)  K-stage   [128][LDT=40]   (dies before S1: frags pre-loaded)
//   [10240,15360) prod      [128][LDT=40]   (post-S2c .. out-proj)
//   [15360,15376) red2      float[8]        (LN only)
//   [0,16384)     P         [128][128] swz  (post-S2a .. PV)
//   [16384,20480) vT        [32][128]  swz  (proj .. PV)
#define LDT 40
#define KOFF 5120
#define POFF 10240
#define RED2 15360
#define VOFF 16384

__global__ void cvt_w(const float* __restrict__ wq, const float* __restrict__ wk,
                      const float* __restrict__ wv, const float* __restrict__ wo,
                      __bf16* __restrict__ ws) {
  int i = blockIdx.x * blockDim.x + threadIdx.x;  // 0..32767
  const float* src = (i < 8192) ? wq : (i < 16384) ? wk : (i < 24576) ? wv : wo;
  ws[i] = (__bf16)src[i & 8191];
}

__global__ __launch_bounds__(TPB, 4) void mha_fused(
    const float* __restrict__ x, const float* __restrict__ gamma,
    const float* __restrict__ beta, const float* __restrict__ bq,
    const float* __restrict__ bk, const float* __restrict__ bv,
    const float* __restrict__ bo, const __bf16* __restrict__ wbf,
    float* __restrict__ out) {
  __shared__ __align__(16) __bf16 R[20480];  // exactly 40960 B -> 4 blocks/CU

  const int b = blockIdx.x;
  const int tid = threadIdx.x;
  const int lane = tid & 63;
  const int wid = tid >> 6;   // 4 waves; wave w owns rows [32w, 32w+32)
  const int l15 = lane & 15;
  const int lh = lane >> 4;   // 0..3
  const int sw = (l15 & 7) << 3;  // XOR swizzle (elems) for 256B-stride tiles

  const __bf16* wqb = wbf;
  const __bf16* wkb = wbf + 8192;
  const __bf16* wvb = wbf + 16384;
  const __bf16* wob = wbf + 24576;  // [32][256] row-major

  const float* xb = x + b * INSZ;
  const f32x4 fz = {0.f, 0.f, 0.f, 0.f};
  // 1/sqrt(32) * log2(e): scores pre-scaled for exp2; softmax uses m=0
  // (shift-invariant; |scores| O(5) for LN'd data, no overflow risk).
  const float CQ = 0.2550564403f;

  float* red2 = (float*)&R[RED2];

  // ---------------- LayerNorm ----------------
  float xv[16];
  float s = 0.f, sq = 0.f;
#pragma unroll
  for (int i = 0; i < 4; ++i) {
    float4 a = ((const float4*)(xb + tid * 16))[i];
    xv[4 * i] = a.x; xv[4 * i + 1] = a.y; xv[4 * i + 2] = a.z; xv[4 * i + 3] = a.w;
  }
#pragma unroll
  for (int i = 0; i < 16; ++i) { s += xv[i]; sq += xv[i] * xv[i]; }
#pragma unroll
  for (int o = 32; o > 0; o >>= 1) { s += __shfl_down(s, o); sq += __shfl_down(sq, o); }
  if (lane == 0) { red2[wid] = s; red2[4 + wid] = sq; }
  __syncthreads();
  s = red2[0] + red2[1] + red2[2] + red2[3];
  sq = red2[4] + red2[5] + red2[6] + red2[7];
  const float mu = s * (1.f / INSZ);
  const float var = fmaxf(sq * (1.f / INSZ) - mu * mu, 0.f);
  const float rs = rsqrtf(var + 1e-5f);
  {
    int base = tid * 16;
#pragma unroll
    for (int i = 0; i < 4; ++i) {
      float4 g4 = ((const float4*)(gamma + base))[i];
      float4 b4 = ((const float4*)(beta + base))[i];
      float gg[4] = {g4.x, g4.y, g4.z, g4.w};
      float bb[4] = {b4.x, b4.y, b4.z, b4.w};
#pragma unroll
      for (int k = 0; k < 4; ++k) {
        int idx = base + 4 * i + k;
        float xn = (xv[4 * i + k] - mu) * rs * gg[k] + bb[k];
        R[(idx >> 5) * LDT + (idx & 31)] = (__bf16)xn;  // wave-local rows
      }
    }
  }
  // No barrier: xn rows are wave-local (written and read by the same wave).

  f32x4 oacc[2][2];
#pragma unroll
  for (int i = 0; i < 2; ++i)
#pragma unroll
    for (int j = 0; j < 2; ++j) oacc[i][j] = fz;

  const int r0 = wid * 32;

  // xn fragments are head-invariant: hoist to registers; xn region dies here.
  bf16x8 tA0 = *(const bf16x8*)&R[(r0 + l15) * LDT + lh * 8];
  bf16x8 tA1 = *(const bf16x8*)&R[(r0 + 16 + l15) * LDT + lh * 8];

  for (int h = 0; h < NH; ++h) {
    // ---------- Q,K projections, transposed MFMA: D[f][s] = W·xn^T ----------
#pragma unroll
    for (int ft = 0; ft < 2; ++ft) {
      int f0 = h * 32 + ft * 16;
      bf16x8 wqf = *(const bf16x8*)&wqb[(f0 + l15) * 32 + lh * 8];
      bf16x8 wkf = *(const bf16x8*)&wkb[(f0 + l15) * 32 + lh * 8];
      f32x4 bq4 = *(const f32x4*)&bq[f0 + lh * 4];
      f32x4 bk4 = *(const f32x4*)&bk[f0 + lh * 4];
#pragma unroll
      for (int st = 0; st < 2; ++st) {
        bf16x8 tB = (st == 0) ? tA0 : tA1;
        f32x4 dq = __builtin_amdgcn_mfma_f32_16x16x32_bf16(wqf, tB, fz, 0, 0, 0);
        f32x4 dk = __builtin_amdgcn_mfma_f32_16x16x32_bf16(wkf, tB, fz, 0, 0, 0);
        bf16x4 pq, pk;
#pragma unroll
        for (int r = 0; r < 4; ++r) {
          pq[r] = (__bf16)((dq[r] + bq4[r]) * CQ);
          pk[r] = (__bf16)(dk[r] + bk4[r]);
        }
        *(bf16x4*)&R[(r0 + st * 16 + l15) * LDT + ft * 16 + lh * 4] = pq;         // q
        *(bf16x4*)&R[KOFF + (r0 + st * 16 + l15) * LDT + ft * 16 + lh * 4] = pk;  // K
      }
    }
    // ---------- V projection: D[s][f], packed store into swizzled vT[f][s] ----------
#pragma unroll
    for (int nt = 0; nt < 2; ++nt) {
      int f0 = h * 32 + nt * 16;
      bf16x8 wvf = *(const bf16x8*)&wvb[(f0 + l15) * 32 + lh * 8];
      float bvs = bv[f0 + l15];
#pragma unroll
      for (int mt = 0; mt < 2; ++mt) {
        bf16x8 tA = (mt == 0) ? tA0 : tA1;
        f32x4 dv = __builtin_amdgcn_mfma_f32_16x16x32_bf16(tA, wvf, fz, 0, 0, 0);
        bf16x4 pv;
#pragma unroll
        for (int r = 0; r < 4; ++r) pv[r] = (__bf16)(dv[r] + bvs);
        *(bf16x4*)&R[VOFF + (nt * 16 + l15) * 128 + ((r0 + mt * 16 + lh * 4) ^ sw)] = pv;
      }
    }
    // K fragments are wave-local: load before the barrier (K region dead after).
    bf16x8 ka0 = *(const bf16x8*)&R[KOFF + (r0 + l15) * LDT + lh * 8];
    bf16x8 ka1 = *(const bf16x8*)&R[KOFF + (r0 + 16 + l15) * LDT + lh * 8];
    __syncthreads();  // S1: q + vT ready for cross-wave reads

    // ---------- scoresT = K·q^T : D[j][i], wave-local over all queries ----------
    // lane reg r: j = r0 + mt*16 + lh*4 + r, i = it*16 + l15
    f32x4 st_[2][8];
    __builtin_amdgcn_s_setprio(1);
#pragma unroll
    for (int it = 0; it < 8; ++it) {
      bf16x8 qb = *(const bf16x8*)&R[(it * 16 + l15) * LDT + lh * 8];
      st_[0][it] = __builtin_amdgcn_mfma_f32_16x16x32_bf16(ka0, qb, fz, 0, 0, 0);
      st_[1][it] = __builtin_amdgcn_mfma_f32_16x16x32_bf16(ka1, qb, fz, 0, 0, 0);
    }
    __builtin_amdgcn_s_setprio(0);

    // ---------- softmax over query axis (m=0): P = exp2(s'), col sums ----------
    float inv[2][4];
#pragma unroll
    for (int mt = 0; mt < 2; ++mt)
#pragma unroll
      for (int r = 0; r < 4; ++r) {
        float ssum = 0.f;
#pragma unroll
        for (int it = 0; it < 8; ++it) {
          float e = __builtin_amdgcn_exp2f(st_[mt][it][r]);
          st_[mt][it][r] = e;
          ssum += e;
        }
#pragma unroll
        for (int o = 1; o < 16; o <<= 1) ssum += __shfl_xor(ssum, o, 64);
        inv[mt][r] = __builtin_amdgcn_rcpf(ssum);
      }
    __syncthreads();  // S2a: all q reads done; P may overwrite q/K/prod/red2

    // ---------- P store: normalized, [query][key] swizzled, packed b64 ----------
#pragma unroll
    for (int mt = 0; mt < 2; ++mt)
#pragma unroll
      for (int it = 0; it < 8; ++it) {
        bf16x4 pp;
#pragma unroll
        for (int r = 0; r < 4; ++r) pp[r] = (__bf16)(st_[mt][it][r] * inv[mt][r]);
        *(bf16x4*)&R[(it * 16 + l15) * 128 + ((r0 + mt * 16 + lh * 4) ^ sw)] = pp;
      }
    __syncthreads();  // S2b: P ready

    // ---------- PV: D[e][q] = vT·P^T ----------
    f32x4 p2[2][2];
#pragma unroll
    for (int i = 0; i < 2; ++i)
#pragma unroll
      for (int j = 0; j < 2; ++j) p2[i][j] = fz;
    __builtin_amdgcn_s_setprio(1);
#pragma unroll
    for (int kc = 0; kc < 4; ++kc) {
      bf16x8 pb0 = *(const bf16x8*)&R[(r0 + l15) * 128 + ((kc * 32 + lh * 8) ^ sw)];
      bf16x8 pb1 = *(const bf16x8*)&R[(r0 + 16 + l15) * 128 + ((kc * 32 + lh * 8) ^ sw)];
      bf16x8 va0 = *(const bf16x8*)&R[VOFF + (l15) * 128 + ((kc * 32 + lh * 8) ^ sw)];
      bf16x8 va1 = *(const bf16x8*)&R[VOFF + (16 + l15) * 128 + ((kc * 32 + lh * 8) ^ sw)];
      p2[0][0] = __builtin_amdgcn_mfma_f32_16x16x32_bf16(va0, pb0, p2[0][0], 0, 0, 0);
      p2[0][1] = __builtin_amdgcn_mfma_f32_16x16x32_bf16(va0, pb1, p2[0][1], 0, 0, 0);
      p2[1][0] = __builtin_amdgcn_mfma_f32_16x16x32_bf16(va1, pb0, p2[1][0], 0, 0, 0);
      p2[1][1] = __builtin_amdgcn_mfma_f32_16x16x32_bf16(va1, pb1, p2[1][1], 0, 0, 0);
    }
    __builtin_amdgcn_s_setprio(0);
    __syncthreads();  // S2c: all PV reads of P/vT done; prod may land inside P

    // ---------- prod stash (wave-local) + out += prod @ wo_h^T ----------
    // lane reg r: e = et*16 + lh*4 + r (consecutive), q = r0 + qt*16 + l15
#pragma unroll
    for (int et = 0; et < 2; ++et)
#pragma unroll
      for (int qt = 0; qt < 2; ++qt) {
        bf16x4 pp;
#pragma unroll
        for (int r = 0; r < 4; ++r) pp[r] = (__bf16)p2[et][qt][r];
        *(bf16x4*)&R[POFF + (r0 + qt * 16 + l15) * LDT + et * 16 + lh * 4] = pp;
      }
    {
      bf16x8 wo0 = *(const bf16x8*)&wob[(l15) * 256 + h * 32 + lh * 8];
      bf16x8 wo1 = *(const bf16x8*)&wob[(16 + l15) * 256 + h * 32 + lh * 8];
#pragma unroll
      for (int mt = 0; mt < 2; ++mt) {
        bf16x8 aa = *(const bf16x8*)&R[POFF + (r0 + mt * 16 + l15) * LDT + lh * 8];
        oacc[mt][0] = __builtin_amdgcn_mfma_f32_16x16x32_bf16(aa, wo0, oacc[mt][0], 0, 0, 0);
        oacc[mt][1] = __builtin_amdgcn_mfma_f32_16x16x32_bf16(aa, wo1, oacc[mt][1], 0, 0, 0);
      }
    }
    // No trailing barrier: next head's q/K/vT writes don't touch prod bytes,
    // and S1 orders them before any cross-wave read.
  }

  // ---------------- epilogue: + bo + x ----------------
#pragma unroll
  for (int mt = 0; mt < 2; ++mt)
#pragma unroll
    for (int nt = 0; nt < 2; ++nt)
#pragma unroll
      for (int r = 0; r < 4; ++r) {
        int s_ = r0 + mt * 16 + lh * 4 + r;
        int e_ = nt * 16 + l15;
        int idx = s_ * 32 + e_;
        out[b * INSZ + idx] = oacc[mt][nt][r] + bo[e_] + xb[idx];
      }
}

extern "C" void kernel_launch(void* const* d_in, const int* in_sizes, int n_in,
                              void* d_out, int out_size, void* d_ws, size_t ws_size,
                              hipStream_t stream) {
  const float* x = (const float*)d_in[0];
  const float* gamma = (const float*)d_in[1];
  const float* beta = (const float*)d_in[2];
  const float* wq = (const float*)d_in[3];
  const float* bq = (const float*)d_in[4];
  const float* wk = (const float*)d_in[5];
  const float* bk = (const float*)d_in[6];
  const float* wv = (const float*)d_in[7];
  const float* bv = (const float*)d_in[8];
  const float* wo = (const float*)d_in[9];
  const float* bo = (const float*)d_in[10];
  float* out = (float*)d_out;
  __bf16* wsb = (__bf16*)d_ws;

  cvt_w<<<128, 256, 0, stream>>>(wq, wk, wv, wo, wsb);
  mha_fused<<<BATCH, TPB, 0, stream>>>(x, gamma, beta, bq, bk, bv, bo, wsb, out);
}

// Round 6
// 70.677 us; speedup vs baseline: 1.1032x; 1.1032x over previous
//
#include <hip/hip_runtime.h>

#define BATCH 1024
#define INSZ 4096
#define SQ 128
#define EM 32
#define NH 8
#define TPB 256

typedef __attribute__((ext_vector_type(8))) __bf16 bf16x8;
typedef __attribute__((ext_vector_type(4))) __bf16 bf16x4;
typedef __attribute__((ext_vector_type(4))) float f32x4;

// One unified 40960-byte LDS region (elem offsets), disjoint lifetimes:
//   [0,5120)      q-stage   [128][LDT=40]   (xn pre-loop; q per head, dies at S2a)
//   [5120,10240)  K-stage   [128][LDT=40]   (dies before S1: frags pre-loaded)
//   [10240,15360) prod      [128][LDT=40]   (post-S2c .. out-proj)
//   [15360,15376) red2      float[8]        (LN only)
//   [0,16384)     P         [128][128] swz  (post-S2a .. PV)
//   [16384,20480) vT        [32][128]  swz  (proj .. PV)
#define LDT 40
#define KOFF 5120
#define POFF 10240
#define RED2 15360
#define VOFF 16384

__global__ void cvt_w(const float* __restrict__ wq, const float* __restrict__ wk,
                      const float* __restrict__ wv, const float* __restrict__ wo,
                      __bf16* __restrict__ ws) {
  int i = blockIdx.x * blockDim.x + threadIdx.x;  // 0..32767
  const float* src = (i < 8192) ? wq : (i < 16384) ? wk : (i < 24576) ? wv : wo;
  ws[i] = (__bf16)src[i & 8191];
}

// Butterfly sum over each 16-lane row, entirely on the VALU pipe (DPP) —
// no LDS/ds_swizzle traffic. Masks {1,2,7,15} pair-combine: after xor1+xor2
// every lane holds its quad sum; xor7 (row_half_mirror) merges the two quads
// of each 8-group; xor15 (row_mirror) merges the two 8-groups. All lanes end
// with the full 16-sum (broadcast included).
__device__ __forceinline__ float row_reduce_add16(float v) {
  int t;
  t = __builtin_amdgcn_update_dpp(0, __float_as_int(v), 0xB1, 0xF, 0xF, true);   // quad_perm [1,0,3,2]
  v += __int_as_float(t);
  t = __builtin_amdgcn_update_dpp(0, __float_as_int(v), 0x4E, 0xF, 0xF, true);   // quad_perm [2,3,0,1]
  v += __int_as_float(t);
  t = __builtin_amdgcn_update_dpp(0, __float_as_int(v), 0x141, 0xF, 0xF, true);  // row_half_mirror
  v += __int_as_float(t);
  t = __builtin_amdgcn_update_dpp(0, __float_as_int(v), 0x140, 0xF, 0xF, true);  // row_mirror
  v += __int_as_float(t);
  return v;
}

__global__ __launch_bounds__(TPB, 3) void mha_fused(
    const float* __restrict__ x, const float* __restrict__ gamma,
    const float* __restrict__ beta, const float* __restrict__ bq,
    const float* __restrict__ bk, const float* __restrict__ bv,
    const float* __restrict__ bo, const __bf16* __restrict__ wbf,
    float* __restrict__ out) {
  __shared__ __align__(16) __bf16 R[20480];  // 40960 B

  const int b = blockIdx.x;
  const int tid = threadIdx.x;
  const int lane = tid & 63;
  const int wid = tid >> 6;   // 4 waves; wave w owns rows [32w, 32w+32)
  const int l15 = lane & 15;
  const int lh = lane >> 4;   // 0..3
  const int sw = (l15 & 7) << 3;  // XOR swizzle (elems) for 256B-stride tiles

  const __bf16* wqb = wbf;
  const __bf16* wkb = wbf + 8192;
  const __bf16* wvb = wbf + 16384;
  const __bf16* wob = wbf + 24576;  // [32][256] row-major

  const float* xb = x + b * INSZ;
  const f32x4 fz = {0.f, 0.f, 0.f, 0.f};
  // 1/sqrt(32) * log2(e): scores pre-scaled for exp2; softmax uses m=0
  // (shift-invariant; |scores| O(5) for LN'd data, no overflow risk).
  const float CQ = 0.2550564403f;

  float* red2 = (float*)&R[RED2];

  // ---------------- LayerNorm ----------------
  float xv[16];
  float s = 0.f, sq = 0.f;
#pragma unroll
  for (int i = 0; i < 4; ++i) {
    float4 a = ((const float4*)(xb + tid * 16))[i];
    xv[4 * i] = a.x; xv[4 * i + 1] = a.y; xv[4 * i + 2] = a.z; xv[4 * i + 3] = a.w;
  }
#pragma unroll
  for (int i = 0; i < 16; ++i) { s += xv[i]; sq += xv[i] * xv[i]; }
#pragma unroll
  for (int o = 32; o > 0; o >>= 1) { s += __shfl_down(s, o); sq += __shfl_down(sq, o); }
  if (lane == 0) { red2[wid] = s; red2[4 + wid] = sq; }
  __syncthreads();
  s = red2[0] + red2[1] + red2[2] + red2[3];
  sq = red2[4] + red2[5] + red2[6] + red2[7];
  const float mu = s * (1.f / INSZ);
  const float var = fmaxf(sq * (1.f / INSZ) - mu * mu, 0.f);
  const float rs = rsqrtf(var + 1e-5f);
  {
    int base = tid * 16;
#pragma unroll
    for (int i = 0; i < 4; ++i) {
      float4 g4 = ((const float4*)(gamma + base))[i];
      float4 b4 = ((const float4*)(beta + base))[i];
      float gg[4] = {g4.x, g4.y, g4.z, g4.w};
      float bb[4] = {b4.x, b4.y, b4.z, b4.w};
#pragma unroll
      for (int k = 0; k < 4; ++k) {
        int idx = base + 4 * i + k;
        float xn = (xv[4 * i + k] - mu) * rs * gg[k] + bb[k];
        R[(idx >> 5) * LDT + (idx & 31)] = (__bf16)xn;  // wave-local rows
      }
    }
  }
  // No barrier: xn rows are wave-local (written and read by the same wave).

  f32x4 oacc[2][2];
#pragma unroll
  for (int i = 0; i < 2; ++i)
#pragma unroll
    for (int j = 0; j < 2; ++j) oacc[i][j] = fz;

  const int r0 = wid * 32;

  // xn fragments are head-invariant: hoist to registers; xn region dies here.
  bf16x8 tA0 = *(const bf16x8*)&R[(r0 + l15) * LDT + lh * 8];
  bf16x8 tA1 = *(const bf16x8*)&R[(r0 + 16 + l15) * LDT + lh * 8];

  for (int h = 0; h < NH; ++h) {
    // ---------- Q,K projections, transposed MFMA: D[f][s] = W·xn^T ----------
#pragma unroll
    for (int ft = 0; ft < 2; ++ft) {
      int f0 = h * 32 + ft * 16;
      bf16x8 wqf = *(const bf16x8*)&wqb[(f0 + l15) * 32 + lh * 8];
      bf16x8 wkf = *(const bf16x8*)&wkb[(f0 + l15) * 32 + lh * 8];
      f32x4 bq4 = *(const f32x4*)&bq[f0 + lh * 4];
      f32x4 bk4 = *(const f32x4*)&bk[f0 + lh * 4];
#pragma unroll
      for (int st = 0; st < 2; ++st) {
        bf16x8 tB = (st == 0) ? tA0 : tA1;
        f32x4 dq = __builtin_amdgcn_mfma_f32_16x16x32_bf16(wqf, tB, fz, 0, 0, 0);
        f32x4 dk = __builtin_amdgcn_mfma_f32_16x16x32_bf16(wkf, tB, fz, 0, 0, 0);
        bf16x4 pq, pk;
#pragma unroll
        for (int r = 0; r < 4; ++r) {
          pq[r] = (__bf16)((dq[r] + bq4[r]) * CQ);
          pk[r] = (__bf16)(dk[r] + bk4[r]);
        }
        *(bf16x4*)&R[(r0 + st * 16 + l15) * LDT + ft * 16 + lh * 4] = pq;         // q
        *(bf16x4*)&R[KOFF + (r0 + st * 16 + l15) * LDT + ft * 16 + lh * 4] = pk;  // K
      }
    }
    // ---------- V projection: D[s][f], packed store into swizzled vT[f][s] ----------
#pragma unroll
    for (int nt = 0; nt < 2; ++nt) {
      int f0 = h * 32 + nt * 16;
      bf16x8 wvf = *(const bf16x8*)&wvb[(f0 + l15) * 32 + lh * 8];
      float bvs = bv[f0 + l15];
#pragma unroll
      for (int mt = 0; mt < 2; ++mt) {
        bf16x8 tA = (mt == 0) ? tA0 : tA1;
        f32x4 dv = __builtin_amdgcn_mfma_f32_16x16x32_bf16(tA, wvf, fz, 0, 0, 0);
        bf16x4 pv;
#pragma unroll
        for (int r = 0; r < 4; ++r) pv[r] = (__bf16)(dv[r] + bvs);
        *(bf16x4*)&R[VOFF + (nt * 16 + l15) * 128 + ((r0 + mt * 16 + lh * 4) ^ sw)] = pv;
      }
    }
    // K fragments are wave-local: load before the barrier (K region dead after).
    bf16x8 ka0 = *(const bf16x8*)&R[KOFF + (r0 + l15) * LDT + lh * 8];
    bf16x8 ka1 = *(const bf16x8*)&R[KOFF + (r0 + 16 + l15) * LDT + lh * 8];
    __syncthreads();  // S1: q + vT ready for cross-wave reads

    // ---------- scoresT = K·q^T : D[j][i], wave-local over all queries ----------
    // lane reg r: j = r0 + mt*16 + lh*4 + r, i = it*16 + l15
    f32x4 st_[2][8];
    __builtin_amdgcn_s_setprio(1);
#pragma unroll
    for (int it = 0; it < 8; ++it) {
      bf16x8 qb = *(const bf16x8*)&R[(it * 16 + l15) * LDT + lh * 8];
      st_[0][it] = __builtin_amdgcn_mfma_f32_16x16x32_bf16(ka0, qb, fz, 0, 0, 0);
      st_[1][it] = __builtin_amdgcn_mfma_f32_16x16x32_bf16(ka1, qb, fz, 0, 0, 0);
    }
    __builtin_amdgcn_s_setprio(0);

    // PV's vT fragments only depend on S1 — hoist the reads here so they
    // overlap the softmax VALU work instead of the post-S2b critical path.
    bf16x8 va[2][4];
#pragma unroll
    for (int kc = 0; kc < 4; ++kc) {
      va[0][kc] = *(const bf16x8*)&R[VOFF + (l15) * 128 + ((kc * 32 + lh * 8) ^ sw)];
      va[1][kc] = *(const bf16x8*)&R[VOFF + (16 + l15) * 128 + ((kc * 32 + lh * 8) ^ sw)];
    }

    // ---------- softmax over query axis (m=0): P = exp2(s'), col sums ----------
    // Reduction over the 16 i-lanes via DPP butterfly (VALU pipe, no LDS).
    float inv[2][4];
#pragma unroll
    for (int mt = 0; mt < 2; ++mt)
#pragma unroll
      for (int r = 0; r < 4; ++r) {
        float ssum = 0.f;
#pragma unroll
        for (int it = 0; it < 8; ++it) {
          float e = __builtin_amdgcn_exp2f(st_[mt][it][r]);
          st_[mt][it][r] = e;
          ssum += e;
        }
        ssum = row_reduce_add16(ssum);
        inv[mt][r] = __builtin_amdgcn_rcpf(ssum);
      }
    __syncthreads();  // S2a: all q reads done; P may overwrite q/K/prod/red2

    // ---------- P store: normalized, [query][key] swizzled, packed b64 ----------
#pragma unroll
    for (int mt = 0; mt < 2; ++mt)
#pragma unroll
      for (int it = 0; it < 8; ++it) {
        bf16x4 pp;
#pragma unroll
        for (int r = 0; r < 4; ++r) pp[r] = (__bf16)(st_[mt][it][r] * inv[mt][r]);
        *(bf16x4*)&R[(it * 16 + l15) * 128 + ((r0 + mt * 16 + lh * 4) ^ sw)] = pp;
      }
    __syncthreads();  // S2b: P ready

    // ---------- PV: D[e][q] = vT·P^T ----------
    f32x4 p2[2][2];
#pragma unroll
    for (int i = 0; i < 2; ++i)
#pragma unroll
      for (int j = 0; j < 2; ++j) p2[i][j] = fz;
    __builtin_amdgcn_s_setprio(1);
#pragma unroll
    for (int kc = 0; kc < 4; ++kc) {
      bf16x8 pb0 = *(const bf16x8*)&R[(r0 + l15) * 128 + ((kc * 32 + lh * 8) ^ sw)];
      bf16x8 pb1 = *(const bf16x8*)&R[(r0 + 16 + l15) * 128 + ((kc * 32 + lh * 8) ^ sw)];
      p2[0][0] = __builtin_amdgcn_mfma_f32_16x16x32_bf16(va[0][kc], pb0, p2[0][0], 0, 0, 0);
      p2[0][1] = __builtin_amdgcn_mfma_f32_16x16x32_bf16(va[0][kc], pb1, p2[0][1], 0, 0, 0);
      p2[1][0] = __builtin_amdgcn_mfma_f32_16x16x32_bf16(va[1][kc], pb0, p2[1][0], 0, 0, 0);
      p2[1][1] = __builtin_amdgcn_mfma_f32_16x16x32_bf16(va[1][kc], pb1, p2[1][1], 0, 0, 0);
    }
    __builtin_amdgcn_s_setprio(0);
    __syncthreads();  // S2c: all PV reads of P/vT done; prod may land inside P

    // ---------- prod stash (wave-local) + out += prod @ wo_h^T ----------
    // lane reg r: e = et*16 + lh*4 + r (consecutive), q = r0 + qt*16 + l15
#pragma unroll
    for (int et = 0; et < 2; ++et)
#pragma unroll
      for (int qt = 0; qt < 2; ++qt) {
        bf16x4 pp;
#pragma unroll
        for (int r = 0; r < 4; ++r) pp[r] = (__bf16)p2[et][qt][r];
        *(bf16x4*)&R[POFF + (r0 + qt * 16 + l15) * LDT + et * 16 + lh * 4] = pp;
      }
    {
      bf16x8 wo0 = *(const bf16x8*)&wob[(l15) * 256 + h * 32 + lh * 8];
      bf16x8 wo1 = *(const bf16x8*)&wob[(16 + l15) * 256 + h * 32 + lh * 8];
#pragma unroll
      for (int mt = 0; mt < 2; ++mt) {
        bf16x8 aa = *(const bf16x8*)&R[POFF + (r0 + mt * 16 + l15) * LDT + lh * 8];
        oacc[mt][0] = __builtin_amdgcn_mfma_f32_16x16x32_bf16(aa, wo0, oacc[mt][0], 0, 0, 0);
        oacc[mt][1] = __builtin_amdgcn_mfma_f32_16x16x32_bf16(aa, wo1, oacc[mt][1], 0, 0, 0);
      }
    }
    // No trailing barrier: next head's q/K/vT writes don't touch prod bytes,
    // and S1 orders them before any cross-wave read.
  }

  // ---------------- epilogue: + bo + x ----------------
#pragma unroll
  for (int mt = 0; mt < 2; ++mt)
#pragma unroll
    for (int nt = 0; nt < 2; ++nt)
#pragma unroll
      for (int r = 0; r < 4; ++r) {
        int s_ = r0 + mt * 16 + lh * 4 + r;
        int e_ = nt * 16 + l15;
        int idx = s_ * 32 + e_;
        out[b * INSZ + idx] = oacc[mt][nt][r] + bo[e_] + xb[idx];
      }
}

extern "C" void kernel_launch(void* const* d_in, const int* in_sizes, int n_in,
                              void* d_out, int out_size, void* d_ws, size_t ws_size,
                              hipStream_t stream) {
  const float* x = (const float*)d_in[0];
  const float* gamma = (const float*)d_in[1];
  const float* beta = (const float*)d_in[2];
  const float* wq = (const float*)d_in[3];
  const float* bq = (const float*)d_in[4];
  const float* wk = (const float*)d_in[5];
  const float* bk = (const float*)d_in[6];
  const float* wv = (const float*)d_in[7];
  const float* bv = (const float*)d_in[8];
  const float* wo = (const float*)d_in[9];
  const float* bo = (const float*)d_in[10];
  float* out = (float*)d_out;
  __bf16* wsb = (__bf16*)d_ws;

  cvt_w<<<128, 256, 0, stream>>>(wq, wk, wv, wo, wsb);
  mha_fused<<<BATCH, TPB, 0, stream>>>(x, gamma, beta, bq, bk, bv, bo, wsb, out);
}

// Round 9
// 64.535 us; speedup vs baseline: 1.2082x; 1.0952x over previous
//
#include <hip/hip_runtime.h>

#define BATCH 1024
#define INSZ 4096
#define SQ 128
#define EM 32
#define NH 8
#define TPB 256

typedef __attribute__((ext_vector_type(8))) __bf16 bf16x8;
typedef __attribute__((ext_vector_type(4))) __bf16 bf16x4;
typedef __attribute__((ext_vector_type(4))) float f32x4;

// Unified LDS region, element offsets (bf16). Audited sizes:
//   Q0 [0,5120)       q-stage parity0 [128][LDT=40] (xn overlay pre-loop)
//   Q1 [5120,10240)   q-stage parity1
//   KP [10240,15360)  K-stage & prod [128][LDT] — strictly wave-local rows;
//                     K in [A(h),B(h)) (consumed to regs), prod in [B(h),A(h+1))
//   V0 [15360,19456)  vT parity0 [32][128] swizzled (4096)
//   V1 [19456,23552)  vT parity1 (4096)
//   PO [23552,39936)  P [128][128] swizzled (16384!) — single buffer; A(h+1)
//                     separates PV(h) reads from P-store(h+1) writes
//   RD [39936,39952)  LN reduction scratch (32 B)
// Total 39952 elems = 79904 B -> 2 blocks/CU (occupancy-invariant per r4-6).
#define LDT 40
#define Q0 0
#define Q1 5120
#define KP 10240
#define V0 15360
#define V1 19456
#define PO 23552
#define RD 39936

// 1/sqrt(32) * log2(e): folded into wq (cvt_w) and bq seed; scores emerge
// pre-scaled for exp2. Softmax uses m=0 (shift-invariant, |scores| O(5)).
#define CQ 0.25505644061151687f

__global__ void cvt_w(const float* __restrict__ wq, const float* __restrict__ wk,
                      const float* __restrict__ wv, const float* __restrict__ wo,
                      __bf16* __restrict__ ws) {
  int i = blockIdx.x * blockDim.x + threadIdx.x;  // 0..32767
  const float* src = (i < 8192) ? wq : (i < 16384) ? wk : (i < 24576) ? wv : wo;
  float v = src[i & 8191];
  if (i < 8192) v *= CQ;  // fold softmax scale into wq
  ws[i] = (__bf16)v;
}

// 16-lane butterfly sum on the VALU pipe (DPP), no LDS traffic.
__device__ __forceinline__ float row_reduce_add16(float v) {
  int t;
  t = __builtin_amdgcn_update_dpp(0, __float_as_int(v), 0xB1, 0xF, 0xF, true);   // quad_perm [1,0,3,2]
  v += __int_as_float(t);
  t = __builtin_amdgcn_update_dpp(0, __float_as_int(v), 0x4E, 0xF, 0xF, true);   // quad_perm [2,3,0,1]
  v += __int_as_float(t);
  t = __builtin_amdgcn_update_dpp(0, __float_as_int(v), 0x141, 0xF, 0xF, true);  // row_half_mirror
  v += __int_as_float(t);
  t = __builtin_amdgcn_update_dpp(0, __float_as_int(v), 0x140, 0xF, 0xF, true);  // row_mirror
  v += __int_as_float(t);
  return v;
}

__global__ __launch_bounds__(TPB, 2) void mha_fused(
    const float* __restrict__ x, const float* __restrict__ gamma,
    const float* __restrict__ beta, const float* __restrict__ bq,
    const float* __restrict__ bk, const float* __restrict__ bv,
    const float* __restrict__ bo, const __bf16* __restrict__ wbf,
    float* __restrict__ out) {
  __shared__ __align__(16) __bf16 R[39952];  // 79904 B

  const int b = blockIdx.x;
  const int tid = threadIdx.x;
  const int lane = tid & 63;
  const int wid = tid >> 6;   // 4 waves; wave w owns s-rows [32w, 32w+32)
  const int l15 = lane & 15;
  const int lh = lane >> 4;   // 0..3
  const int sw = (l15 & 7) << 3;  // XOR swizzle (elems) for 256B-stride tiles

  const __bf16* wqb = wbf;
  const __bf16* wkb = wbf + 8192;
  const __bf16* wvb = wbf + 16384;
  const __bf16* wob = wbf + 24576;  // [32][256] row-major

  const float* xb = x + b * INSZ;
  const f32x4 fz = {0.f, 0.f, 0.f, 0.f};

  float* red2 = (float*)&R[RD];

  // ---------------- LayerNorm ----------------
  float xv[16];
  float s = 0.f, sq = 0.f;
#pragma unroll
  for (int i = 0; i < 4; ++i) {
    float4 a = ((const float4*)(xb + tid * 16))[i];
    xv[4 * i] = a.x; xv[4 * i + 1] = a.y; xv[4 * i + 2] = a.z; xv[4 * i + 3] = a.w;
  }
#pragma unroll
  for (int i = 0; i < 16; ++i) { s += xv[i]; sq += xv[i] * xv[i]; }
#pragma unroll
  for (int o = 32; o > 0; o >>= 1) { s += __shfl_down(s, o); sq += __shfl_down(sq, o); }
  if (lane == 0) { red2[wid] = s; red2[4 + wid] = sq; }
  __syncthreads();
  s = red2[0] + red2[1] + red2[2] + red2[3];
  sq = red2[4] + red2[5] + red2[6] + red2[7];
  const float mu = s * (1.f / INSZ);
  const float var = fmaxf(sq * (1.f / INSZ) - mu * mu, 0.f);
  const float rs = rsqrtf(var + 1e-5f);
  {
    int base = tid * 16;
#pragma unroll
    for (int i = 0; i < 4; ++i) {
      float4 g4 = ((const float4*)(gamma + base))[i];
      float4 b4 = ((const float4*)(beta + base))[i];
      float gg[4] = {g4.x, g4.y, g4.z, g4.w};
      float bb[4] = {b4.x, b4.y, b4.z, b4.w};
#pragma unroll
      for (int k = 0; k < 4; ++k) {
        int idx = base + 4 * i + k;
        float xn = (xv[4 * i + k] - mu) * rs * gg[k] + bb[k];
        R[Q0 + (idx >> 5) * LDT + (idx & 31)] = (__bf16)xn;  // wave-local rows
      }
    }
  }
  // No barrier: xn rows are wave-local (written and read by the same wave).

  const int r0 = wid * 32;

  // xn fragments are head-invariant: hoist to regs; xn (Q0 overlay) dies here.
  bf16x8 tA0 = *(const bf16x8*)&R[Q0 + (r0 + l15) * LDT + lh * 8];
  bf16x8 tA1 = *(const bf16x8*)&R[Q0 + (r0 + 16 + l15) * LDT + lh * 8];

  // out accumulator seeded with bo (C/D col = e = nt*16+l15, uniform over regs)
  f32x4 oacc[2][2];
  {
    float b0 = bo[l15], b1 = bo[16 + l15];
#pragma unroll
    for (int mt = 0; mt < 2; ++mt) {
      oacc[mt][0] = f32x4{b0, b0, b0, b0};
      oacc[mt][1] = f32x4{b1, b1, b1, b1};
    }
  }

  bf16x8 ka0, ka1;

  // Project head hh into q[qo], vT[vo], K (KP); biases folded into MFMA C-in.
  auto do_proj = [&](int hh, int qo, int vo) {
#pragma unroll
    for (int ft = 0; ft < 2; ++ft) {
      int f0 = hh * 32 + ft * 16;
      bf16x8 wqf = *(const bf16x8*)&wqb[(f0 + l15) * 32 + lh * 8];
      bf16x8 wkf = *(const bf16x8*)&wkb[(f0 + l15) * 32 + lh * 8];
      f32x4 bq4 = *(const f32x4*)&bq[f0 + lh * 4];
      f32x4 bk4 = *(const f32x4*)&bk[f0 + lh * 4];
#pragma unroll
      for (int r = 0; r < 4; ++r) bq4[r] *= CQ;
#pragma unroll
      for (int st = 0; st < 2; ++st) {
        bf16x8 tB = (st == 0) ? tA0 : tA1;
        // D[f][s]: row=f=ft*16+lh*4+r, col=s=r0+st*16+l15; C seeds = bias(f)
        f32x4 dq = __builtin_amdgcn_mfma_f32_16x16x32_bf16(wqf, tB, bq4, 0, 0, 0);
        f32x4 dk = __builtin_amdgcn_mfma_f32_16x16x32_bf16(wkf, tB, bk4, 0, 0, 0);
        bf16x4 pq, pk;
#pragma unroll
        for (int r = 0; r < 4; ++r) { pq[r] = (__bf16)dq[r]; pk[r] = (__bf16)dk[r]; }
        *(bf16x4*)&R[qo + (r0 + st * 16 + l15) * LDT + ft * 16 + lh * 4] = pq;
        *(bf16x4*)&R[KP + (r0 + st * 16 + l15) * LDT + ft * 16 + lh * 4] = pk;
      }
    }
#pragma unroll
    for (int nt = 0; nt < 2; ++nt) {
      int f0 = hh * 32 + nt * 16;
      bf16x8 wvf = *(const bf16x8*)&wvb[(f0 + l15) * 32 + lh * 8];
      float bvs = bv[f0 + l15];
      f32x4 bv4 = {bvs, bvs, bvs, bvs};  // D[s][f]: col=f=f0+l15, uniform over regs
#pragma unroll
      for (int mt = 0; mt < 2; ++mt) {
        bf16x8 tA = (mt == 0) ? tA0 : tA1;
        f32x4 dv = __builtin_amdgcn_mfma_f32_16x16x32_bf16(tA, wvf, bv4, 0, 0, 0);
        bf16x4 pv;
#pragma unroll
        for (int r = 0; r < 4; ++r) pv[r] = (__bf16)dv[r];
        *(bf16x4*)&R[vo + (nt * 16 + l15) * 128 + ((r0 + mt * 16 + lh * 4) ^ sw)] = pv;
      }
    }
    // K fragments: wave-local rows, consumed straight back into registers;
    // the KP region is then free for the prod stash after barrier B.
    ka0 = *(const bf16x8*)&R[KP + (r0 + l15) * LDT + lh * 8];
    ka1 = *(const bf16x8*)&R[KP + (r0 + 16 + l15) * LDT + lh * 8];
  };

  // Prologue: project head 0 into parity-0 buffers.
  do_proj(0, Q0, V0);

  for (int h = 0; h < NH; ++h) {
    const int p = h & 1;
    const int qo = p ? Q1 : Q0;
    const int vo = p ? V1 : V0;
    __syncthreads();  // A: q[p] + vT[p] ready (written before this barrier)

    // ---------- scoresT = K·q^T : D[j][i], j=r0+mt*16+lh*4+r, i=it*16+l15 ----------
    f32x4 st_[2][8];
    __builtin_amdgcn_s_setprio(1);
#pragma unroll
    for (int it = 0; it < 8; ++it) {
      bf16x8 qb = *(const bf16x8*)&R[qo + (it * 16 + l15) * LDT + lh * 8];
      st_[0][it] = __builtin_amdgcn_mfma_f32_16x16x32_bf16(ka0, qb, fz, 0, 0, 0);
      st_[1][it] = __builtin_amdgcn_mfma_f32_16x16x32_bf16(ka1, qb, fz, 0, 0, 0);
    }
    // ---------- project NEXT head into opposite buffers (pipelined) ----------
    if (h < NH - 1) do_proj(h + 1, p ? Q0 : Q1, p ? V0 : V1);
    __builtin_amdgcn_s_setprio(0);

    // PV's vT fragments depend only on barrier A — prefetch during softmax.
    bf16x8 va[2][4];
#pragma unroll
    for (int kc = 0; kc < 4; ++kc) {
      va[0][kc] = *(const bf16x8*)&R[vo + (l15) * 128 + ((kc * 32 + lh * 8) ^ sw)];
      va[1][kc] = *(const bf16x8*)&R[vo + (16 + l15) * 128 + ((kc * 32 + lh * 8) ^ sw)];
    }

    // ---------- softmax over query axis (m=0): P = exp2(s'), DPP col sums ----------
    float inv[2][4];
#pragma unroll
    for (int mt = 0; mt < 2; ++mt)
#pragma unroll
      for (int r = 0; r < 4; ++r) {
        float ssum = 0.f;
#pragma unroll
        for (int it = 0; it < 8; ++it) {
          float e = __builtin_amdgcn_exp2f(st_[mt][it][r]);
          st_[mt][it][r] = e;
          ssum += e;
        }
        ssum = row_reduce_add16(ssum);
        inv[mt][r] = __builtin_amdgcn_rcpf(ssum);
      }

    // ---------- P store: normalized, [query][key] swizzled, packed b64 ----------
#pragma unroll
    for (int mt = 0; mt < 2; ++mt)
#pragma unroll
      for (int it = 0; it < 8; ++it) {
        bf16x4 pp;
#pragma unroll
        for (int r = 0; r < 4; ++r) pp[r] = (__bf16)(st_[mt][it][r] * inv[mt][r]);
        *(bf16x4*)&R[PO + (it * 16 + l15) * 128 + ((r0 + mt * 16 + lh * 4) ^ sw)] = pp;
      }
    __syncthreads();  // B: P ready

    // ---------- PV: D[e][q] = vT·P^T ----------
    f32x4 p2[2][2];
#pragma unroll
    for (int i = 0; i < 2; ++i)
#pragma unroll
      for (int j = 0; j < 2; ++j) p2[i][j] = fz;
    __builtin_amdgcn_s_setprio(1);
#pragma unroll
    for (int kc = 0; kc < 4; ++kc) {
      bf16x8 pb0 = *(const bf16x8*)&R[PO + (r0 + l15) * 128 + ((kc * 32 + lh * 8) ^ sw)];
      bf16x8 pb1 = *(const bf16x8*)&R[PO + (r0 + 16 + l15) * 128 + ((kc * 32 + lh * 8) ^ sw)];
      p2[0][0] = __builtin_amdgcn_mfma_f32_16x16x32_bf16(va[0][kc], pb0, p2[0][0], 0, 0, 0);
      p2[0][1] = __builtin_amdgcn_mfma_f32_16x16x32_bf16(va[0][kc], pb1, p2[0][1], 0, 0, 0);
      p2[1][0] = __builtin_amdgcn_mfma_f32_16x16x32_bf16(va[1][kc], pb0, p2[1][0], 0, 0, 0);
      p2[1][1] = __builtin_amdgcn_mfma_f32_16x16x32_bf16(va[1][kc], pb1, p2[1][1], 0, 0, 0);
    }
    __builtin_amdgcn_s_setprio(0);

    // ---------- prod stash (wave-local rows, reuses KP) + out += prod @ wo_h^T ----------
#pragma unroll
    for (int et = 0; et < 2; ++et)
#pragma unroll
      for (int qt = 0; qt < 2; ++qt) {
        bf16x4 pp;
#pragma unroll
        for (int r = 0; r < 4; ++r) pp[r] = (__bf16)p2[et][qt][r];
        *(bf16x4*)&R[KP + (r0 + qt * 16 + l15) * LDT + et * 16 + lh * 4] = pp;
      }
    {
      bf16x8 wo0 = *(const bf16x8*)&wob[(l15) * 256 + h * 32 + lh * 8];
      bf16x8 wo1 = *(const bf16x8*)&wob[(16 + l15) * 256 + h * 32 + lh * 8];
#pragma unroll
      for (int mt = 0; mt < 2; ++mt) {
        bf16x8 aa = *(const bf16x8*)&R[KP + (r0 + mt * 16 + l15) * LDT + lh * 8];
        oacc[mt][0] = __builtin_amdgcn_mfma_f32_16x16x32_bf16(aa, wo0, oacc[mt][0], 0, 0, 0);
        oacc[mt][1] = __builtin_amdgcn_mfma_f32_16x16x32_bf16(aa, wo1, oacc[mt][1], 0, 0, 0);
      }
    }
    // No trailing barrier: next iteration's barrier A orders the cross-wave
    // buffers (opposite-parity q/vT; single P re-store happens after A).
  }

  // ---------------- epilogue: + x (bo already seeded) ----------------
#pragma unroll
  for (int mt = 0; mt < 2; ++mt)
#pragma unroll
    for (int nt = 0; nt < 2; ++nt)
#pragma unroll
      for (int r = 0; r < 4; ++r) {
        int s_ = r0 + mt * 16 + lh * 4 + r;
        int e_ = nt * 16 + l15;
        int idx = s_ * 32 + e_;
        out[b * INSZ + idx] = oacc[mt][nt][r] + xb[idx];
      }
}

extern "C" void kernel_launch(void* const* d_in, const int* in_sizes, int n_in,
                              void* d_out, int out_size, void* d_ws, size_t ws_size,
                              hipStream_t stream) {
  const float* x = (const float*)d_in[0];
  const float* gamma = (const float*)d_in[1];
  const float* beta = (const float*)d_in[2];
  const float* wq = (const float*)d_in[3];
  const float* bq = (const float*)d_in[4];
  const float* wk = (const float*)d_in[5];
  const float* bk = (const float*)d_in[6];
  const float* wv = (const float*)d_in[7];
  const float* bv = (const float*)d_in[8];
  const float* wo = (const float*)d_in[9];
  const float* bo = (const float*)d_in[10];
  float* out = (float*)d_out;
  __bf16* wsb = (__bf16*)d_ws;

  cvt_w<<<128, 256, 0, stream>>>(wq, wk, wv, wo, wsb);
  mha_fused<<<BATCH, TPB, 0, stream>>>(x, gamma, beta, bq, bk, bv, bo, wsb, out);
}